// Round 3
// baseline (3102.540 us; speedup 1.0000x reference)
//
#include <hip/hip_runtime.h>
#include <hip/hip_bf16.h>

// MarioDoomPolicyNet: conv stack (4x stride-2 + ELU) -> 2-layer LSTM scan -> heads.
// R2: FULL F32 pipeline. R1's f16 packing gave logits ~0.05 error -> argmax (output 2)
// flips on near-ties. Outputs 0/1 passed at R2 => semantics correct, precision wasn't.
//   k_prep: transpose w_ih0/1, scan-weight relayout [k4][row][4], conv2/3/4 -> [o][tap][i]
//   k_donecvt: auto-detect done encoding (uint8 vs 4-byte), emit notdone floats (verified working)
//   k_conv12: FUSED conv1+conv2 per image; frame tile + act1 tile live in LDS (85KB),
//             avoids materializing 231MB f32 act1
//   k_conv3 / k_conv4: direct conv f32, wave-uniform out-channel group -> scalar weight loads
//   k_gemm: G = X @ w_ihT + b_ih + b_hh for all 4096 rows
//   k_scan: 64 WGs (1/batch elem), only h@w_hh is sequential; f32 weights, coalesced float4
//   k_heads / k_argmax

#define T_ 64
#define B_ 64
#define NTB 4096
#define HID 256
#define G4 1024

__device__ inline float sigm(float x) { return 1.f / (1.f + expf(-x)); }
__device__ inline float elu_(float x) { return x > 0.f ? x : expf(x) - 1.f; }

// ---------------- prep: weight relayouts (all f32) ----------------
__global__ void k_prep(const float* __restrict__ wih0, const float* __restrict__ wih1,
                       const float* __restrict__ whh0, const float* __restrict__ whh1,
                       const float* __restrict__ cw2, const float* __restrict__ cw3,
                       const float* __restrict__ cw4,
                       float* __restrict__ wih0T, float* __restrict__ wih1T,
                       float* __restrict__ wq0, float* __restrict__ wq1,
                       float* __restrict__ wc2, float* __restrict__ wc3,
                       float* __restrict__ wc4) {
  int idx = blockIdx.x * 256 + threadIdx.x;
  if (idx < 294912) {                       // wih0T[k*1024+j] = wih0[j*288+k]
    int k = idx >> 10, j = idx & 1023;
    wih0T[idx] = wih0[j * 288 + k];
  } else if (idx < 557056) {                // wih1T[k*1024+j] = wih1[j*256+k]
    int r = idx - 294912; int k = r >> 10, j = r & 1023;
    wih1T[r] = wih1[j * 256 + k];
  } else if (idx < 819200) {                // wq0[(k4*1024+row)*4+j] = whh0[row][4k4+j]
    int r = idx - 557056;
    int j = r & 3, row = (r >> 2) & 1023, k4 = r >> 12;
    wq0[r] = whh0[row * 256 + k4 * 4 + j];
  } else if (idx < 1081344) {
    int r = idx - 819200;
    int j = r & 3, row = (r >> 2) & 1023, k4 = r >> 12;
    wq1[r] = whh1[row * 256 + k4 * 4 + j];
  } else if (idx < 1108992) {               // conv weights -> [o][tap][i] f32
    int r = idx - 1081344;                  // 3 * 9216
    int which = r / 9216; int d = r - which * 9216;
    int i = d & 31, tap = (d >> 5) % 9, o = d / 288;
    int kh = tap / 3, kw = tap - kh * 3;
    const float* src = which == 0 ? cw2 : (which == 1 ? cw3 : cw4);
    float* dst = which == 0 ? wc2 : (which == 1 ? wc3 : wc4);
    dst[d] = src[((o * 32 + i) * 3 + kh) * 3 + kw];
  }
}

// ---------------- done -> notdone float, robust to encoding (verified R2) ----------------
__global__ __launch_bounds__(1024)
void k_donecvt(const unsigned char* __restrict__ db, float* __restrict__ nd) {
  int tid = threadIdx.x;
  const unsigned* dw = (const unsigned*)db;
  unsigned w = dw[tid];
  int odd = ((w & 0xFFFFFF00u) != 0u && w != 0x3F800000u) ? 1 : 0;
  int any = __syncthreads_count(odd);
  bool u8 = (any > 0);
  for (int j = tid; j < 4096; j += 1024) {
    unsigned v = u8 ? (unsigned)db[j] : dw[j];
    nd[j] = v ? 0.f : 1.f;
  }
}

// ---------------- fused conv1+conv2: frame[n] -> act2[n][11][11][32] f32 ----------------
// NCHW view: x[n][c][A][B] = frame[n][B][A][c].  act1 tile (21x21x32) lives in LDS only.
__global__ __launch_bounds__(256)
void k_conv12(const float* __restrict__ frame, const float* __restrict__ cw1,
              const float* __restrict__ cb1, const float* __restrict__ wc2,
              const float* __restrict__ cb2, float* __restrict__ act2) {
  __shared__ __align__(16) float fr[7056];    // 42*42*4
  __shared__ __align__(16) float a1[14112];   // 21*21*32
  int n = blockIdx.x;
  const float4* fp = (const float4*)(frame + n * 7056);
  for (int i = threadIdx.x; i < 1764; i += 256) ((float4*)fr)[i] = fp[i];
  __syncthreads();

  // stage B: conv1 into LDS. wave w handles o in [8w, 8w+8), lanes stride positions.
  int lane = threadIdx.x & 63, wave = threadIdx.x >> 6;
  {
    int ob = __builtin_amdgcn_readfirstlane(wave << 3);
    const float* wbase = cw1 + ob * 36;       // w[o][c][kh][kw], scalar loads
    for (int s = lane; s < 441; s += 64) {
      int p = s / 21, q = s - (s / 21) * 21;
      float acc[8];
#pragma unroll
      for (int oi = 0; oi < 8; ++oi) acc[oi] = cb1[ob + oi];
#pragma unroll
      for (int kh = 0; kh < 3; ++kh) {
        int A = 2 * p - 1 + kh;
        if ((unsigned)A >= 42u) continue;
#pragma unroll
        for (int kw = 0; kw < 3; ++kw) {
          int Bc = 2 * q - 1 + kw;
          if ((unsigned)Bc >= 42u) continue;
          float4 v = *(const float4*)&fr[(Bc * 42 + A) << 2];
          int tap = kh * 3 + kw;
#pragma unroll
          for (int oi = 0; oi < 8; ++oi) {
            const float* w = wbase + oi * 36 + tap;
            acc[oi] += v.x * w[0] + v.y * w[9] + v.z * w[18] + v.w * w[27];
          }
        }
      }
#pragma unroll
      for (int oi = 0; oi < 8; ++oi)
        a1[(p * 21 + q) * 32 + ob + oi] = elu_(acc[oi]);
    }
  }
  __syncthreads();

  // stage C: conv2 from LDS act1 -> global act2. thread = (position, o-half of 16).
  int s = threadIdx.x & 127, oh = threadIdx.x >> 7;
  if (s < 121) {
    int p = s / 11, q = s - (s / 11) * 11;
    int ob = __builtin_amdgcn_readfirstlane(oh << 4);
    float acc[16];
#pragma unroll
    for (int oi = 0; oi < 16; ++oi) acc[oi] = cb2[ob + oi];
#pragma unroll
    for (int kh = 0; kh < 3; ++kh) {
      int A = 2 * p - 1 + kh;
      if ((unsigned)A >= 21u) continue;
#pragma unroll
      for (int kw = 0; kw < 3; ++kw) {
        int Bc = 2 * q - 1 + kw;
        if ((unsigned)Bc >= 21u) continue;
        const float* ap = &a1[(A * 21 + Bc) * 32];
        const float* wt = wc2 + (ob * 9 + kh * 3 + kw) * 32;   // [o][tap][i], scalar
#pragma unroll
        for (int i4 = 0; i4 < 8; ++i4) {
          float4 v = *(const float4*)&ap[i4 * 4];
#pragma unroll
          for (int oi = 0; oi < 16; ++oi) {
            const float* w = wt + oi * 288 + i4 * 4;
            acc[oi] += v.x * w[0] + v.y * w[1] + v.z * w[2] + v.w * w[3];
          }
        }
      }
    }
#pragma unroll
    for (int oi = 0; oi < 16; ++oi)
      act2[(n * 121 + p * 11 + q) * 32 + ob + oi] = elu_(acc[oi]);
  }
}

// ---------------- conv3: act2 [n][11][11][32] -> act3 [n][6][6][32] f32 ----------------
__global__ void k_conv3(const float* __restrict__ in, const float* __restrict__ wc,
                        const float* __restrict__ bias, float* __restrict__ out) {
  int n = blockIdx.x >> 3, og = blockIdx.x & 7;
  int lane = threadIdx.x & 63;
  int o = __builtin_amdgcn_readfirstlane((og << 2) + (threadIdx.x >> 6));
  float bo = bias[o];
  for (int s = lane; s < 36; s += 64) {
    int p = s / 6, q = s - (s / 6) * 6;
    float acc = bo;
    for (int kh = 0; kh < 3; ++kh) {
      int A = 2 * p - 1 + kh;
      if ((unsigned)A >= 11u) continue;
      for (int kw = 0; kw < 3; ++kw) {
        int Bc = 2 * q - 1 + kw;
        if ((unsigned)Bc >= 11u) continue;
        const float* ip = in + ((n * 11 + A) * 11 + Bc) * 32;
        const float* w = wc + (o * 9 + kh * 3 + kw) * 32;      // scalar loads
#pragma unroll
        for (int i4 = 0; i4 < 8; ++i4) {
          float4 v = *(const float4*)&ip[i4 * 4];
          acc += v.x * w[i4 * 4] + v.y * w[i4 * 4 + 1] + v.z * w[i4 * 4 + 2] + v.w * w[i4 * 4 + 3];
        }
      }
    }
    out[(n * 36 + p * 6 + q) * 32 + o] = elu_(acc);
  }
}

// ---------------- conv4: act3 [n][6][6][32] -> feat [n][288] f32, feat = c*9 + p*3 + q ----------------
__global__ void k_conv4(const float* __restrict__ in, const float* __restrict__ wc,
                        const float* __restrict__ bias, float* __restrict__ feat) {
  int nb = blockIdx.x >> 3, og = blockIdx.x & 7;
  int lane = threadIdx.x & 63;
  int o = __builtin_amdgcn_readfirstlane((og << 2) + (threadIdx.x >> 6));
  if (lane >= 63) return;                   // 7 images x 9 positions per wave
  int n7 = lane / 9;
  int n = nb * 7 + n7;
  if (n >= NTB) return;
  int s = lane - n7 * 9;
  int p = s / 3, q = s - p * 3;
  float acc = bias[o];
  for (int kh = 0; kh < 3; ++kh) {
    int A = 2 * p - 1 + kh;
    if ((unsigned)A >= 6u) continue;
    for (int kw = 0; kw < 3; ++kw) {
      int Bc = 2 * q - 1 + kw;
      if ((unsigned)Bc >= 6u) continue;
      const float* ip = in + ((n * 6 + A) * 6 + Bc) * 32;
      const float* w = wc + (o * 9 + kh * 3 + kw) * 32;
#pragma unroll
      for (int i4 = 0; i4 < 8; ++i4) {
        float4 v = *(const float4*)&ip[i4 * 4];
        acc += v.x * w[i4 * 4] + v.y * w[i4 * 4 + 1] + v.z * w[i4 * 4 + 2] + v.w * w[i4 * 4 + 3];
      }
    }
  }
  feat[n * 288 + o * 9 + s] = elu_(acc);
}

// ---------------- GEMM: out[n][j] = sum_k in[n][k]*wT[k][j] + b1[j]+b2[j]  (n-tile 16) ----------------
__global__ void k_gemm(const float* __restrict__ in, const float* __restrict__ wT,
                       const float* __restrict__ b1, const float* __restrict__ b2,
                       float* __restrict__ out, int K) {
  int jb = blockIdx.x & 3, ng = blockIdx.x >> 2;
  int j = (jb << 8) + threadIdx.x;
  const float* ip = in + ng * 16 * K;       // uniform addresses -> s_load
  float acc[16];
#pragma unroll
  for (int m = 0; m < 16; ++m) acc[m] = 0.f;
  for (int k = 0; k < K; ++k) {
    float wv = wT[k * 1024 + j];
#pragma unroll
    for (int m = 0; m < 16; ++m) acc[m] += ip[m * K + k] * wv;
  }
  float bb = b1[j] + b2[j];
#pragma unroll
  for (int m = 0; m < 16; ++m) out[(ng * 16 + m) * 1024 + j] = acc[m] + bb;
}

// ---------------- LSTM scan (one layer): 64 WGs, 1 batch elem each ----------------
// gates = G[t,b,:] + nd * (whh @ h);  thread tid -> gate rows {tid, tid+512}
//   tid<256: i (tid), g (tid+512);  tid>=256: f (tid), o (tid+512)
// wq layout: wq[(k4*1024+row)*4+j] = whh[row][4k4+j]  -> coalesced float4 per (k4,row)
__global__ __launch_bounds__(512)
void k_scan(const float* __restrict__ wq, const float* __restrict__ G,
            const float* __restrict__ h_init, const float* __restrict__ c_init,
            const float* __restrict__ ndb, float* __restrict__ h_all,
            float* __restrict__ hT, float* __restrict__ cT) {
  int b = blockIdx.x, tid = threadIdx.x;
  __shared__ __align__(16) float hs[256];
  __shared__ float fo[512];
  float c = 0.f;
  if (tid < 256) { hs[tid] = h_init[b * HID + tid]; c = c_init[b * HID + tid]; }
  const float* w0 = wq + tid * 4;
  const float* w1 = wq + (tid + 512) * 4;
  float hlast = 0.f;
  for (int t = 0; t < T_; ++t) {
    __syncthreads();                        // hs ready
    float nd = ndb[t * B_ + b];
    float a0 = 0.f, a1 = 0.f, b0 = 0.f, b1 = 0.f;
#pragma unroll 8
    for (int k4 = 0; k4 < 64; ++k4) {
      float4 h4 = *(const float4*)&hs[k4 * 4];
      float4 wa = *(const float4*)&w0[k4 * 4096];
      float4 wb = *(const float4*)&w1[k4 * 4096];
      a0 += wa.x * h4.x + wa.y * h4.y;
      a1 += wa.z * h4.z + wa.w * h4.w;
      b0 += wb.x * h4.x + wb.y * h4.y;
      b1 += wb.z * h4.z + wb.w * h4.w;
    }
    int gb = (t * B_ + b) * G4 + tid;
    float g0 = G[gb] + (a0 + a1) * nd;
    float g1 = G[gb + 512] + (b0 + b1) * nd;
    if (tid >= 256) {
      fo[tid - 256] = sigm(g0);             // f
      fo[tid] = sigm(g1);                   // o
    }
    __syncthreads();
    if (tid < 256) {
      float si = sigm(g0), sg = tanhf(g1);
      float f = fo[tid], oo = fo[256 + tid];
      c = f * (c * nd) + si * sg;
      float h = oo * tanhf(c);
      h_all[(t * B_ + b) * HID + tid] = h;
      hs[tid] = h;
      hlast = h;
    }
  }
  if (tid < 256) { hT[b * HID + tid] = hlast; cT[b * HID + tid] = c; }
}

// ---------------- heads ----------------
__global__ void k_heads(const float* __restrict__ h1, const float* __restrict__ pw,
                        const float* __restrict__ pb, const float* __restrict__ bw,
                        const float* __restrict__ bb, float* __restrict__ out) {
  int idx = blockIdx.x * 256 + threadIdx.x;       // 53248 = 4096 * 13
  int n = idx / 13, o = idx - n * 13;
  const float* h = h1 + n * HID;
  if (o < 12) {
    float acc = pb[o];
    const float* wr = pw + o * HID;
    for (int k = 0; k < HID; ++k) acc += h[k] * wr[k];
    out[n * 12 + o] = acc;
  } else {
    float acc = bb[0];
    for (int k = 0; k < HID; ++k) acc += h[k] * bw[k];
    out[49152 + n] = acc;
  }
}

__global__ void k_argmax(const float* __restrict__ logits, float* __restrict__ action) {
  int n = blockIdx.x * 256 + threadIdx.x;
  float best = logits[n * 12]; int bi = 0;
  for (int o = 1; o < 12; ++o) {
    float v = logits[n * 12 + o];
    if (v > best) { best = v; bi = o; }             // strict > == first-max-wins
  }
  action[n] = (float)bi;
}

extern "C" void kernel_launch(void* const* d_in, const int* in_sizes, int n_in,
                              void* d_out, int out_size, void* d_ws, size_t ws_size,
                              hipStream_t stream) {
  const float* frame = (const float*)d_in[0];
  const unsigned char* done = (const unsigned char*)d_in[1];
  const float* h0 = (const float*)d_in[2];
  const float* c0 = (const float*)d_in[3];
  const float* cw1 = (const float*)d_in[4];  const float* cb1 = (const float*)d_in[5];
  const float* cw2 = (const float*)d_in[6];  const float* cb2 = (const float*)d_in[7];
  const float* cw3 = (const float*)d_in[8];  const float* cb3 = (const float*)d_in[9];
  const float* cw4 = (const float*)d_in[10]; const float* cb4 = (const float*)d_in[11];
  const float* wih0 = (const float*)d_in[12]; const float* whh0 = (const float*)d_in[13];
  const float* bih0 = (const float*)d_in[14]; const float* bhh0 = (const float*)d_in[15];
  const float* wih1 = (const float*)d_in[16]; const float* whh1 = (const float*)d_in[17];
  const float* bih1 = (const float*)d_in[18]; const float* bhh1 = (const float*)d_in[19];
  const float* pw = (const float*)d_in[20]; const float* pb = (const float*)d_in[21];
  const float* bw = (const float*)d_in[22]; const float* bb = (const float*)d_in[23];

  // workspace layout (~132 MB, all f32)
  float* act2  = (float*)d_ws;                      // 15,859,712
  float* act3  = act2 + 15859712;                   //  4,718,592
  float* feat  = act3 + 4718592;                    //  1,179,648
  float* G0    = feat + 1179648;                    //  4,194,304
  float* G1    = G0 + 4194304;                      //  4,194,304
  float* h0a   = G1 + 4194304;                      //  1,048,576
  float* h1a   = h0a + 1048576;                     //  1,048,576
  float* wih0T = h1a + 1048576;                     //    294,912
  float* wih1T = wih0T + 294912;                    //    262,144
  float* wq0   = wih1T + 262144;                    //    262,144
  float* wq1   = wq0 + 262144;                      //    262,144
  float* wc2   = wq1 + 262144;                      //      9,216
  float* wc3   = wc2 + 9216;
  float* wc4   = wc3 + 9216;
  float* ndb   = wc4 + 9216;                        //      4,096

  float* out = (float*)d_out;
  float* o_hT = out + 57344;
  float* o_cT = out + 90112;

  k_prep<<<4332, 256, 0, stream>>>(wih0, wih1, whh0, whh1, cw2, cw3, cw4,
                                   wih0T, wih1T, wq0, wq1, wc2, wc3, wc4);
  k_donecvt<<<1, 1024, 0, stream>>>(done, ndb);
  k_conv12<<<4096, 256, 0, stream>>>(frame, cw1, cb1, wc2, cb2, act2);
  k_conv3<<<32768, 256, 0, stream>>>(act2, wc3, cb3, act3);
  k_conv4<<<4688, 256, 0, stream>>>(act3, wc4, cb4, feat);
  k_gemm<<<1024, 256, 0, stream>>>(feat, wih0T, bih0, bhh0, G0, 288);
  k_scan<<<64, 512, 0, stream>>>(wq0, G0, h0, c0, ndb, h0a, o_hT, o_cT);
  k_gemm<<<1024, 256, 0, stream>>>(h0a, wih1T, bih1, bhh1, G1, 256);
  k_scan<<<64, 512, 0, stream>>>(wq1, G1, h0 + 16384, c0 + 16384, ndb, h1a,
                                 o_hT + 16384, o_cT + 16384);
  k_heads<<<208, 256, 0, stream>>>(h1a, pw, pb, bw, bb, out);
  k_argmax<<<16, 256, 0, stream>>>(out, out + 53248);
}

// Round 4
// 3062.587 us; speedup vs baseline: 1.0130x; 1.0130x over previous
//
#include <hip/hip_runtime.h>
#include <hip/hip_bf16.h>

// MarioDoomPolicyNet: conv stack (4x stride-2 + ELU) -> 2-layer LSTM scan -> heads.
// R3 passed (f32 pipeline, absmax 0.0039). R4: rebuild k_conv12 (was 764us, 25% of total):
//   - 512 threads (8 waves) instead of 256 -> occupancy 12->25%
//   - conflict-free LDS: frame as per-channel planes [c][A*42+B] (bank stride 2 on reads);
//     act1 as channel-quad-major [oq][pos] float4 (16B lane stride writes, 32B reads)
//   - stage B: thread=position (441/512 active), all 32 o per thread, SGPR weights
//   - stage C: thread=(pos, o-octet) (484/512 active)
//   - act2 stored quad-major [n][oq][121]x4 -> coalesced; conv3 input addressing updated
// Everything else identical to R3 (verified correct).

#define T_ 64
#define B_ 64
#define NTB 4096
#define HID 256
#define G4 1024

__device__ inline float sigm(float x) { return 1.f / (1.f + expf(-x)); }
__device__ inline float elu_(float x) { return x > 0.f ? x : expf(x) - 1.f; }

// ---------------- prep: weight relayouts (all f32) ----------------
__global__ void k_prep(const float* __restrict__ wih0, const float* __restrict__ wih1,
                       const float* __restrict__ whh0, const float* __restrict__ whh1,
                       const float* __restrict__ cw2, const float* __restrict__ cw3,
                       const float* __restrict__ cw4,
                       float* __restrict__ wih0T, float* __restrict__ wih1T,
                       float* __restrict__ wq0, float* __restrict__ wq1,
                       float* __restrict__ wc2, float* __restrict__ wc3,
                       float* __restrict__ wc4) {
  int idx = blockIdx.x * 256 + threadIdx.x;
  if (idx < 294912) {                       // wih0T[k*1024+j] = wih0[j*288+k]
    int k = idx >> 10, j = idx & 1023;
    wih0T[idx] = wih0[j * 288 + k];
  } else if (idx < 557056) {                // wih1T[k*1024+j] = wih1[j*256+k]
    int r = idx - 294912; int k = r >> 10, j = r & 1023;
    wih1T[r] = wih1[j * 256 + k];
  } else if (idx < 819200) {                // wq0[(k4*1024+row)*4+j] = whh0[row][4k4+j]
    int r = idx - 557056;
    int j = r & 3, row = (r >> 2) & 1023, k4 = r >> 12;
    wq0[r] = whh0[row * 256 + k4 * 4 + j];
  } else if (idx < 1081344) {
    int r = idx - 819200;
    int j = r & 3, row = (r >> 2) & 1023, k4 = r >> 12;
    wq1[r] = whh1[row * 256 + k4 * 4 + j];
  } else if (idx < 1108992) {               // conv weights -> [o][tap][i] f32
    int r = idx - 1081344;                  // 3 * 9216
    int which = r / 9216; int d = r - which * 9216;
    int i = d & 31, tap = (d >> 5) % 9, o = d / 288;
    int kh = tap / 3, kw = tap - kh * 3;
    const float* src = which == 0 ? cw2 : (which == 1 ? cw3 : cw4);
    float* dst = which == 0 ? wc2 : (which == 1 ? wc3 : wc4);
    dst[d] = src[((o * 32 + i) * 3 + kh) * 3 + kw];
  }
}

// ---------------- done -> notdone float, robust to encoding (verified) ----------------
__global__ __launch_bounds__(1024)
void k_donecvt(const unsigned char* __restrict__ db, float* __restrict__ nd) {
  int tid = threadIdx.x;
  const unsigned* dw = (const unsigned*)db;
  unsigned w = dw[tid];
  int odd = ((w & 0xFFFFFF00u) != 0u && w != 0x3F800000u) ? 1 : 0;
  int any = __syncthreads_count(odd);
  bool u8 = (any > 0);
  for (int j = tid; j < 4096; j += 1024) {
    unsigned v = u8 ? (unsigned)db[j] : dw[j];
    nd[j] = v ? 0.f : 1.f;
  }
}

// ---------------- fused conv1+conv2: frame[n] -> act2q[n][oq][121] float4 ----------------
// NCHW view: x[n][c][A][B] = frame[n][B][A][c].
__global__ __launch_bounds__(512)
void k_conv12(const float* __restrict__ frame, const float* __restrict__ cw1,
              const float* __restrict__ cb1, const float* __restrict__ wc2,
              const float* __restrict__ cb2, float* __restrict__ act2q) {
  __shared__ float pl[4][1764];                  // [c][A*42+B]  28224 B
  __shared__ __align__(16) float a1t[8][1764];   // [oq][pos*4]  56448 B
  int n = blockIdx.x;
  int tid = threadIdx.x;

  // stage A: frame[n] (layout [B][A][c] float4) -> channel planes pl[c][A*42+B]
  const float4* fp = (const float4*)(frame + n * 7056);
  for (int j = tid; j < 1764; j += 512) {
    float4 v = fp[j];                            // j = B*42 + A
    int A = j % 42, Bq = j / 42;
    int idx = A * 42 + Bq;
    pl[0][idx] = v.x; pl[1][idx] = v.y; pl[2][idx] = v.z; pl[3][idx] = v.w;
  }
  __syncthreads();

  // stage B: conv1, thread = position, computes all 32 o (SGPR weights)
  if (tid < 441) {
    int p = tid / 21, q = tid - (tid / 21) * 21;
    float px[9][4];
#pragma unroll
    for (int kh = 0; kh < 3; ++kh) {
#pragma unroll
      for (int kw = 0; kw < 3; ++kw) {
        int A = 2 * p - 1 + kh, Bc = 2 * q - 1 + kw;
        bool ok = ((unsigned)A < 42u) && ((unsigned)Bc < 42u);
        int idx = ok ? (A * 42 + Bc) : 0;
#pragma unroll
        for (int c = 0; c < 4; ++c) px[kh * 3 + kw][c] = ok ? pl[c][idx] : 0.f;
      }
    }
#pragma unroll
    for (int oq = 0; oq < 8; ++oq) {
      float4 acc;
      float* ap = (float*)&acc;
#pragma unroll
      for (int j = 0; j < 4; ++j) {
        int o = oq * 4 + j;
        float a = cb1[o];
        const float* w = cw1 + o * 36;           // [c][kh][kw]: w[c*9+tap], scalar loads
#pragma unroll
        for (int tap = 0; tap < 9; ++tap)
          a += px[tap][0] * w[tap] + px[tap][1] * w[9 + tap] +
               px[tap][2] * w[18 + tap] + px[tap][3] * w[27 + tap];
        ap[j] = elu_(a);
      }
      *(float4*)&a1t[oq][tid * 4] = acc;         // 16B lane stride: conflict-free
    }
  }
  __syncthreads();

  // stage C: conv2, thread = (pos, o-octet); oh wave-uniform
  int s = tid & 127, oh = tid >> 7;              // oh in 0..3
  if (s < 121) {
    int p = s / 11, q = s - (s / 11) * 11;
    int ob = oh * 8;
    float acc[8];
#pragma unroll
    for (int oi = 0; oi < 8; ++oi) acc[oi] = cb2[ob + oi];
#pragma unroll
    for (int kh = 0; kh < 3; ++kh) {
      int A = 2 * p - 1 + kh;
      if ((unsigned)A >= 21u) continue;
#pragma unroll
      for (int kw = 0; kw < 3; ++kw) {
        int Bc = 2 * q - 1 + kw;
        if ((unsigned)Bc >= 21u) continue;
        int pos = A * 21 + Bc;
        int tap = kh * 3 + kw;
#pragma unroll
        for (int i4 = 0; i4 < 8; ++i4) {
          float4 v = *(const float4*)&a1t[i4][pos * 4];   // 32B lane stride: free
#pragma unroll
          for (int oi = 0; oi < 8; ++oi) {
            const float* w = wc2 + ((ob + oi) * 9 + tap) * 32 + i4 * 4;  // scalar
            acc[oi] += v.x * w[0] + v.y * w[1] + v.z * w[2] + v.w * w[3];
          }
        }
      }
    }
#pragma unroll
    for (int half = 0; half < 2; ++half) {
      float4 o4 = make_float4(elu_(acc[half * 4 + 0]), elu_(acc[half * 4 + 1]),
                              elu_(acc[half * 4 + 2]), elu_(acc[half * 4 + 3]));
      *(float4*)&act2q[(((size_t)n * 8 + oh * 2 + half) * 121 + s) * 4] = o4;
    }
  }
}

// ---------------- conv3: act2q [n][i4][121]x4 -> act3 [n][pos][32] f32 ----------------
__global__ void k_conv3(const float* __restrict__ in, const float* __restrict__ wc,
                        const float* __restrict__ bias, float* __restrict__ out) {
  int n = blockIdx.x >> 3, og = blockIdx.x & 7;
  int lane = threadIdx.x & 63;
  int o = __builtin_amdgcn_readfirstlane((og << 2) + (threadIdx.x >> 6));
  float bo = bias[o];
  for (int s = lane; s < 36; s += 64) {
    int p = s / 6, q = s - (s / 6) * 6;
    float acc = bo;
    for (int kh = 0; kh < 3; ++kh) {
      int A = 2 * p - 1 + kh;
      if ((unsigned)A >= 11u) continue;
      for (int kw = 0; kw < 3; ++kw) {
        int Bc = 2 * q - 1 + kw;
        if ((unsigned)Bc >= 11u) continue;
        int pos = A * 11 + Bc;
        const float* w = wc + (o * 9 + kh * 3 + kw) * 32;      // scalar loads
#pragma unroll
        for (int i4 = 0; i4 < 8; ++i4) {
          float4 v = *(const float4*)&in[(((size_t)n * 8 + i4) * 121 + pos) * 4];
          acc += v.x * w[i4 * 4] + v.y * w[i4 * 4 + 1] + v.z * w[i4 * 4 + 2] + v.w * w[i4 * 4 + 3];
        }
      }
    }
    out[(n * 36 + p * 6 + q) * 32 + o] = elu_(acc);
  }
}

// ---------------- conv4: act3 [n][6][6][32] -> feat [n][288] f32, feat = c*9 + p*3 + q ----------------
__global__ void k_conv4(const float* __restrict__ in, const float* __restrict__ wc,
                        const float* __restrict__ bias, float* __restrict__ feat) {
  int nb = blockIdx.x >> 3, og = blockIdx.x & 7;
  int lane = threadIdx.x & 63;
  int o = __builtin_amdgcn_readfirstlane((og << 2) + (threadIdx.x >> 6));
  if (lane >= 63) return;                   // 7 images x 9 positions per wave
  int n7 = lane / 9;
  int n = nb * 7 + n7;
  if (n >= NTB) return;
  int s = lane - n7 * 9;
  int p = s / 3, q = s - p * 3;
  float acc = bias[o];
  for (int kh = 0; kh < 3; ++kh) {
    int A = 2 * p - 1 + kh;
    if ((unsigned)A >= 6u) continue;
    for (int kw = 0; kw < 3; ++kw) {
      int Bc = 2 * q - 1 + kw;
      if ((unsigned)Bc >= 6u) continue;
      const float* ip = in + ((n * 6 + A) * 6 + Bc) * 32;
      const float* w = wc + (o * 9 + kh * 3 + kw) * 32;
#pragma unroll
      for (int i4 = 0; i4 < 8; ++i4) {
        float4 v = *(const float4*)&ip[i4 * 4];
        acc += v.x * w[i4 * 4] + v.y * w[i4 * 4 + 1] + v.z * w[i4 * 4 + 2] + v.w * w[i4 * 4 + 3];
      }
    }
  }
  feat[n * 288 + o * 9 + s] = elu_(acc);
}

// ---------------- GEMM: out[n][j] = sum_k in[n][k]*wT[k][j] + b1[j]+b2[j]  (n-tile 16) ----------------
__global__ void k_gemm(const float* __restrict__ in, const float* __restrict__ wT,
                       const float* __restrict__ b1, const float* __restrict__ b2,
                       float* __restrict__ out, int K) {
  int jb = blockIdx.x & 3, ng = blockIdx.x >> 2;
  int j = (jb << 8) + threadIdx.x;
  const float* ip = in + ng * 16 * K;       // uniform addresses -> s_load
  float acc[16];
#pragma unroll
  for (int m = 0; m < 16; ++m) acc[m] = 0.f;
  for (int k = 0; k < K; ++k) {
    float wv = wT[k * 1024 + j];
#pragma unroll
    for (int m = 0; m < 16; ++m) acc[m] += ip[m * K + k] * wv;
  }
  float bb = b1[j] + b2[j];
#pragma unroll
  for (int m = 0; m < 16; ++m) out[(ng * 16 + m) * 1024 + j] = acc[m] + bb;
}

// ---------------- LSTM scan (one layer): 64 WGs, 1 batch elem each ----------------
__global__ __launch_bounds__(512)
void k_scan(const float* __restrict__ wq, const float* __restrict__ G,
            const float* __restrict__ h_init, const float* __restrict__ c_init,
            const float* __restrict__ ndb, float* __restrict__ h_all,
            float* __restrict__ hT, float* __restrict__ cT) {
  int b = blockIdx.x, tid = threadIdx.x;
  __shared__ __align__(16) float hs[256];
  __shared__ float fo[512];
  float c = 0.f;
  if (tid < 256) { hs[tid] = h_init[b * HID + tid]; c = c_init[b * HID + tid]; }
  const float* w0 = wq + tid * 4;
  const float* w1 = wq + (tid + 512) * 4;
  float hlast = 0.f;
  for (int t = 0; t < T_; ++t) {
    __syncthreads();                        // hs ready
    float nd = ndb[t * B_ + b];
    float a0 = 0.f, a1 = 0.f, b0 = 0.f, b1 = 0.f;
#pragma unroll 8
    for (int k4 = 0; k4 < 64; ++k4) {
      float4 h4 = *(const float4*)&hs[k4 * 4];
      float4 wa = *(const float4*)&w0[k4 * 4096];
      float4 wb = *(const float4*)&w1[k4 * 4096];
      a0 += wa.x * h4.x + wa.y * h4.y;
      a1 += wa.z * h4.z + wa.w * h4.w;
      b0 += wb.x * h4.x + wb.y * h4.y;
      b1 += wb.z * h4.z + wb.w * h4.w;
    }
    int gb = (t * B_ + b) * G4 + tid;
    float g0 = G[gb] + (a0 + a1) * nd;
    float g1 = G[gb + 512] + (b0 + b1) * nd;
    if (tid >= 256) {
      fo[tid - 256] = sigm(g0);             // f
      fo[tid] = sigm(g1);                   // o
    }
    __syncthreads();
    if (tid < 256) {
      float si = sigm(g0), sg = tanhf(g1);
      float f = fo[tid], oo = fo[256 + tid];
      c = f * (c * nd) + si * sg;
      float h = oo * tanhf(c);
      h_all[(t * B_ + b) * HID + tid] = h;
      hs[tid] = h;
      hlast = h;
    }
  }
  if (tid < 256) { hT[b * HID + tid] = hlast; cT[b * HID + tid] = c; }
}

// ---------------- heads ----------------
__global__ void k_heads(const float* __restrict__ h1, const float* __restrict__ pw,
                        const float* __restrict__ pb, const float* __restrict__ bw,
                        const float* __restrict__ bb, float* __restrict__ out) {
  int idx = blockIdx.x * 256 + threadIdx.x;       // 53248 = 4096 * 13
  int n = idx / 13, o = idx - n * 13;
  const float* h = h1 + n * HID;
  if (o < 12) {
    float acc = pb[o];
    const float* wr = pw + o * HID;
    for (int k = 0; k < HID; ++k) acc += h[k] * wr[k];
    out[n * 12 + o] = acc;
  } else {
    float acc = bb[0];
    for (int k = 0; k < HID; ++k) acc += h[k] * bw[k];
    out[49152 + n] = acc;
  }
}

__global__ void k_argmax(const float* __restrict__ logits, float* __restrict__ action) {
  int n = blockIdx.x * 256 + threadIdx.x;
  float best = logits[n * 12]; int bi = 0;
  for (int o = 1; o < 12; ++o) {
    float v = logits[n * 12 + o];
    if (v > best) { best = v; bi = o; }             // strict > == first-max-wins
  }
  action[n] = (float)bi;
}

extern "C" void kernel_launch(void* const* d_in, const int* in_sizes, int n_in,
                              void* d_out, int out_size, void* d_ws, size_t ws_size,
                              hipStream_t stream) {
  const float* frame = (const float*)d_in[0];
  const unsigned char* done = (const unsigned char*)d_in[1];
  const float* h0 = (const float*)d_in[2];
  const float* c0 = (const float*)d_in[3];
  const float* cw1 = (const float*)d_in[4];  const float* cb1 = (const float*)d_in[5];
  const float* cw2 = (const float*)d_in[6];  const float* cb2 = (const float*)d_in[7];
  const float* cw3 = (const float*)d_in[8];  const float* cb3 = (const float*)d_in[9];
  const float* cw4 = (const float*)d_in[10]; const float* cb4 = (const float*)d_in[11];
  const float* wih0 = (const float*)d_in[12]; const float* whh0 = (const float*)d_in[13];
  const float* bih0 = (const float*)d_in[14]; const float* bhh0 = (const float*)d_in[15];
  const float* wih1 = (const float*)d_in[16]; const float* whh1 = (const float*)d_in[17];
  const float* bih1 = (const float*)d_in[18]; const float* bhh1 = (const float*)d_in[19];
  const float* pw = (const float*)d_in[20]; const float* pb = (const float*)d_in[21];
  const float* bw = (const float*)d_in[22]; const float* bb = (const float*)d_in[23];

  // workspace layout (~132 MB, all f32)
  float* act2  = (float*)d_ws;                      // 15,859,712 (quad-major [n][8][121]x4)
  float* act3  = act2 + 15859712;                   //  4,718,592
  float* feat  = act3 + 4718592;                    //  1,179,648
  float* G0    = feat + 1179648;                    //  4,194,304
  float* G1    = G0 + 4194304;                      //  4,194,304
  float* h0a   = G1 + 4194304;                      //  1,048,576
  float* h1a   = h0a + 1048576;                     //  1,048,576
  float* wih0T = h1a + 1048576;                     //    294,912
  float* wih1T = wih0T + 294912;                    //    262,144
  float* wq0   = wih1T + 262144;                    //    262,144
  float* wq1   = wq0 + 262144;                      //    262,144
  float* wc2   = wq1 + 262144;                      //      9,216
  float* wc3   = wc2 + 9216;
  float* wc4   = wc3 + 9216;
  float* ndb   = wc4 + 9216;                        //      4,096

  float* out = (float*)d_out;
  float* o_hT = out + 57344;
  float* o_cT = out + 90112;

  k_prep<<<4332, 256, 0, stream>>>(wih0, wih1, whh0, whh1, cw2, cw3, cw4,
                                   wih0T, wih1T, wq0, wq1, wc2, wc3, wc4);
  k_donecvt<<<1, 1024, 0, stream>>>(done, ndb);
  k_conv12<<<4096, 512, 0, stream>>>(frame, cw1, cb1, wc2, cb2, act2);
  k_conv3<<<32768, 256, 0, stream>>>(act2, wc3, cb3, act3);
  k_conv4<<<4688, 256, 0, stream>>>(act3, wc4, cb4, feat);
  k_gemm<<<1024, 256, 0, stream>>>(feat, wih0T, bih0, bhh0, G0, 288);
  k_scan<<<64, 512, 0, stream>>>(wq0, G0, h0, c0, ndb, h0a, o_hT, o_cT);
  k_gemm<<<1024, 256, 0, stream>>>(h0a, wih1T, bih1, bhh1, G1, 256);
  k_scan<<<64, 512, 0, stream>>>(wq1, G1, h0 + 16384, c0 + 16384, ndb, h1a,
                                 o_hT + 16384, o_cT + 16384);
  k_heads<<<208, 256, 0, stream>>>(h1a, pw, pb, bw, bb, out);
  k_argmax<<<16, 256, 0, stream>>>(out, out + 53248);
}

// Round 5
// 2757.096 us; speedup vs baseline: 1.1253x; 1.1108x over previous
//
#include <hip/hip_runtime.h>
#include <hip/hip_bf16.h>

// MarioDoomPolicyNet: conv stack (4x stride-2 + ELU) -> 2-layer LSTM scan -> heads.
// R3 passed (764us conv12, scalar weights, 16-way LDS conflicts).
// R4 regressed conv12 to 980us: dropped readfirstlane on stage-C ob -> compiler emitted
//   per-lane vector loads for conv2 weights (VALU cycles ~2x). Conflicts did drop 7.8e7->2.1e7.
// R5: restore readfirstlane (scalar s_load weights) + swizzle a1t col (4*pos + 4*(pos>>3))
//   to kill the residual 8-way write conflicts. Only k_conv12 touched vs R4.

#define T_ 64
#define B_ 64
#define NTB 4096
#define HID 256
#define G4 1024

__device__ inline float sigm(float x) { return 1.f / (1.f + expf(-x)); }
__device__ inline float elu_(float x) { return x > 0.f ? x : expf(x) - 1.f; }

// ---------------- prep: weight relayouts (all f32) ----------------
__global__ void k_prep(const float* __restrict__ wih0, const float* __restrict__ wih1,
                       const float* __restrict__ whh0, const float* __restrict__ whh1,
                       const float* __restrict__ cw2, const float* __restrict__ cw3,
                       const float* __restrict__ cw4,
                       float* __restrict__ wih0T, float* __restrict__ wih1T,
                       float* __restrict__ wq0, float* __restrict__ wq1,
                       float* __restrict__ wc2, float* __restrict__ wc3,
                       float* __restrict__ wc4) {
  int idx = blockIdx.x * 256 + threadIdx.x;
  if (idx < 294912) {                       // wih0T[k*1024+j] = wih0[j*288+k]
    int k = idx >> 10, j = idx & 1023;
    wih0T[idx] = wih0[j * 288 + k];
  } else if (idx < 557056) {                // wih1T[k*1024+j] = wih1[j*256+k]
    int r = idx - 294912; int k = r >> 10, j = r & 1023;
    wih1T[r] = wih1[j * 256 + k];
  } else if (idx < 819200) {                // wq0[(k4*1024+row)*4+j] = whh0[row][4k4+j]
    int r = idx - 557056;
    int j = r & 3, row = (r >> 2) & 1023, k4 = r >> 12;
    wq0[r] = whh0[row * 256 + k4 * 4 + j];
  } else if (idx < 1081344) {
    int r = idx - 819200;
    int j = r & 3, row = (r >> 2) & 1023, k4 = r >> 12;
    wq1[r] = whh1[row * 256 + k4 * 4 + j];
  } else if (idx < 1108992) {               // conv weights -> [o][tap][i] f32
    int r = idx - 1081344;                  // 3 * 9216
    int which = r / 9216; int d = r - which * 9216;
    int i = d & 31, tap = (d >> 5) % 9, o = d / 288;
    int kh = tap / 3, kw = tap - kh * 3;
    const float* src = which == 0 ? cw2 : (which == 1 ? cw3 : cw4);
    float* dst = which == 0 ? wc2 : (which == 1 ? wc3 : wc4);
    dst[d] = src[((o * 32 + i) * 3 + kh) * 3 + kw];
  }
}

// ---------------- done -> notdone float, robust to encoding (verified) ----------------
__global__ __launch_bounds__(1024)
void k_donecvt(const unsigned char* __restrict__ db, float* __restrict__ nd) {
  int tid = threadIdx.x;
  const unsigned* dw = (const unsigned*)db;
  unsigned w = dw[tid];
  int odd = ((w & 0xFFFFFF00u) != 0u && w != 0x3F800000u) ? 1 : 0;
  int any = __syncthreads_count(odd);
  bool u8 = (any > 0);
  for (int j = tid; j < 4096; j += 1024) {
    unsigned v = u8 ? (unsigned)db[j] : dw[j];
    nd[j] = v ? 0.f : 1.f;
  }
}

// ---------------- fused conv1+conv2: frame[n] -> act2q[n][oq][121] float4 ----------------
// NCHW view: x[n][c][A][B] = frame[n][B][A][c].
// a1t column swizzle: col(pos) = 4*pos + 4*(pos>>3)  (16B-aligned, breaks bank-stride-4)
#define A1COL(pos) (((pos) << 2) + (((pos) >> 3) << 2))
__global__ __launch_bounds__(512)
void k_conv12(const float* __restrict__ frame, const float* __restrict__ cw1,
              const float* __restrict__ cb1, const float* __restrict__ wc2,
              const float* __restrict__ cb2, float* __restrict__ act2q) {
  __shared__ float pl[4][1764];                  // [c][A*42+B]  28224 B
  __shared__ __align__(16) float a1t[8][1984];   // [oq][swizzled pos*4]  63488 B
  int n = blockIdx.x;
  int tid = threadIdx.x;

  // stage A: frame[n] (layout [B][A][c] float4) -> channel planes pl[c][A*42+B]
  const float4* fp = (const float4*)(frame + n * 7056);
  for (int j = tid; j < 1764; j += 512) {
    float4 v = fp[j];                            // j = B*42 + A
    int A = j % 42, Bq = j / 42;
    int idx = A * 42 + Bq;
    pl[0][idx] = v.x; pl[1][idx] = v.y; pl[2][idx] = v.z; pl[3][idx] = v.w;
  }
  __syncthreads();

  // stage B: conv1, thread = position, computes all 32 o (SGPR weights)
  if (tid < 441) {
    int p = tid / 21, q = tid - (tid / 21) * 21;
    float px[9][4];
#pragma unroll
    for (int kh = 0; kh < 3; ++kh) {
#pragma unroll
      for (int kw = 0; kw < 3; ++kw) {
        int A = 2 * p - 1 + kh, Bc = 2 * q - 1 + kw;
        bool ok = ((unsigned)A < 42u) && ((unsigned)Bc < 42u);
        int idx = ok ? (A * 42 + Bc) : 0;
#pragma unroll
        for (int c = 0; c < 4; ++c) px[kh * 3 + kw][c] = ok ? pl[c][idx] : 0.f;
      }
    }
    int col = A1COL(tid);
#pragma unroll
    for (int oq = 0; oq < 8; ++oq) {
      float4 acc;
      float* ap = (float*)&acc;
#pragma unroll
      for (int j = 0; j < 4; ++j) {
        int o = oq * 4 + j;
        float a = cb1[o];
        const float* w = cw1 + o * 36;           // [c][kh][kw]: w[c*9+tap], scalar loads
#pragma unroll
        for (int tap = 0; tap < 9; ++tap)
          a += px[tap][0] * w[tap] + px[tap][1] * w[9 + tap] +
               px[tap][2] * w[18 + tap] + px[tap][3] * w[27 + tap];
        ap[j] = elu_(a);
      }
      *(float4*)&a1t[oq][col] = acc;             // swizzled: conflict-free
    }
  }
  __syncthreads();

  // stage C: conv2, thread = (pos, o-octet); ob forced wave-uniform -> scalar weight loads
  int s = tid & 127, oh = tid >> 7;              // oh in 0..3, uniform per wave
  int ob = __builtin_amdgcn_readfirstlane(oh << 3);
  if (s < 121) {
    int p = s / 11, q = s - (s / 11) * 11;
    float acc[8];
#pragma unroll
    for (int oi = 0; oi < 8; ++oi) acc[oi] = cb2[ob + oi];
#pragma unroll
    for (int kh = 0; kh < 3; ++kh) {
      int A = 2 * p - 1 + kh;
      if ((unsigned)A >= 21u) continue;
#pragma unroll
      for (int kw = 0; kw < 3; ++kw) {
        int Bc = 2 * q - 1 + kw;
        if ((unsigned)Bc >= 21u) continue;
        int pos = A * 21 + Bc;
        int col = A1COL(pos);
        int tap = kh * 3 + kw;
#pragma unroll
        for (int i4 = 0; i4 < 8; ++i4) {
          float4 v = *(const float4*)&a1t[i4][col];
#pragma unroll
          for (int oi = 0; oi < 8; ++oi) {
            const float* w = wc2 + ((ob + oi) * 9 + tap) * 32 + i4 * 4;  // s_load
            acc[oi] += v.x * w[0] + v.y * w[1] + v.z * w[2] + v.w * w[3];
          }
        }
      }
    }
#pragma unroll
    for (int half = 0; half < 2; ++half) {
      float4 o4 = make_float4(elu_(acc[half * 4 + 0]), elu_(acc[half * 4 + 1]),
                              elu_(acc[half * 4 + 2]), elu_(acc[half * 4 + 3]));
      *(float4*)&act2q[(((size_t)n * 8 + (ob >> 2) + half) * 121 + s) * 4] = o4;
    }
  }
}

// ---------------- conv3: act2q [n][i4][121]x4 -> act3 [n][pos][32] f32 ----------------
__global__ void k_conv3(const float* __restrict__ in, const float* __restrict__ wc,
                        const float* __restrict__ bias, float* __restrict__ out) {
  int n = blockIdx.x >> 3, og = blockIdx.x & 7;
  int lane = threadIdx.x & 63;
  int o = __builtin_amdgcn_readfirstlane((og << 2) + (threadIdx.x >> 6));
  float bo = bias[o];
  for (int s = lane; s < 36; s += 64) {
    int p = s / 6, q = s - (s / 6) * 6;
    float acc = bo;
    for (int kh = 0; kh < 3; ++kh) {
      int A = 2 * p - 1 + kh;
      if ((unsigned)A >= 11u) continue;
      for (int kw = 0; kw < 3; ++kw) {
        int Bc = 2 * q - 1 + kw;
        if ((unsigned)Bc >= 11u) continue;
        int pos = A * 11 + Bc;
        const float* w = wc + (o * 9 + kh * 3 + kw) * 32;      // scalar loads
#pragma unroll
        for (int i4 = 0; i4 < 8; ++i4) {
          float4 v = *(const float4*)&in[(((size_t)n * 8 + i4) * 121 + pos) * 4];
          acc += v.x * w[i4 * 4] + v.y * w[i4 * 4 + 1] + v.z * w[i4 * 4 + 2] + v.w * w[i4 * 4 + 3];
        }
      }
    }
    out[(n * 36 + p * 6 + q) * 32 + o] = elu_(acc);
  }
}

// ---------------- conv4: act3 [n][6][6][32] -> feat [n][288] f32, feat = c*9 + p*3 + q ----------------
__global__ void k_conv4(const float* __restrict__ in, const float* __restrict__ wc,
                        const float* __restrict__ bias, float* __restrict__ feat) {
  int nb = blockIdx.x >> 3, og = blockIdx.x & 7;
  int lane = threadIdx.x & 63;
  int o = __builtin_amdgcn_readfirstlane((og << 2) + (threadIdx.x >> 6));
  if (lane >= 63) return;                   // 7 images x 9 positions per wave
  int n7 = lane / 9;
  int n = nb * 7 + n7;
  if (n >= NTB) return;
  int s = lane - n7 * 9;
  int p = s / 3, q = s - p * 3;
  float acc = bias[o];
  for (int kh = 0; kh < 3; ++kh) {
    int A = 2 * p - 1 + kh;
    if ((unsigned)A >= 6u) continue;
    for (int kw = 0; kw < 3; ++kw) {
      int Bc = 2 * q - 1 + kw;
      if ((unsigned)Bc >= 6u) continue;
      const float* ip = in + ((n * 6 + A) * 6 + Bc) * 32;
      const float* w = wc + (o * 9 + kh * 3 + kw) * 32;
#pragma unroll
      for (int i4 = 0; i4 < 8; ++i4) {
        float4 v = *(const float4*)&ip[i4 * 4];
        acc += v.x * w[i4 * 4] + v.y * w[i4 * 4 + 1] + v.z * w[i4 * 4 + 2] + v.w * w[i4 * 4 + 3];
      }
    }
  }
  feat[n * 288 + o * 9 + s] = elu_(acc);
}

// ---------------- GEMM: out[n][j] = sum_k in[n][k]*wT[k][j] + b1[j]+b2[j]  (n-tile 16) ----------------
__global__ void k_gemm(const float* __restrict__ in, const float* __restrict__ wT,
                       const float* __restrict__ b1, const float* __restrict__ b2,
                       float* __restrict__ out, int K) {
  int jb = blockIdx.x & 3, ng = blockIdx.x >> 2;
  int j = (jb << 8) + threadIdx.x;
  const float* ip = in + ng * 16 * K;       // uniform addresses -> s_load
  float acc[16];
#pragma unroll
  for (int m = 0; m < 16; ++m) acc[m] = 0.f;
  for (int k = 0; k < K; ++k) {
    float wv = wT[k * 1024 + j];
#pragma unroll
    for (int m = 0; m < 16; ++m) acc[m] += ip[m * K + k] * wv;
  }
  float bb = b1[j] + b2[j];
#pragma unroll
  for (int m = 0; m < 16; ++m) out[(ng * 16 + m) * 1024 + j] = acc[m] + bb;
}

// ---------------- LSTM scan (one layer): 64 WGs, 1 batch elem each ----------------
__global__ __launch_bounds__(512)
void k_scan(const float* __restrict__ wq, const float* __restrict__ G,
            const float* __restrict__ h_init, const float* __restrict__ c_init,
            const float* __restrict__ ndb, float* __restrict__ h_all,
            float* __restrict__ hT, float* __restrict__ cT) {
  int b = blockIdx.x, tid = threadIdx.x;
  __shared__ __align__(16) float hs[256];
  __shared__ float fo[512];
  float c = 0.f;
  if (tid < 256) { hs[tid] = h_init[b * HID + tid]; c = c_init[b * HID + tid]; }
  const float* w0 = wq + tid * 4;
  const float* w1 = wq + (tid + 512) * 4;
  float hlast = 0.f;
  for (int t = 0; t < T_; ++t) {
    __syncthreads();                        // hs ready
    float nd = ndb[t * B_ + b];
    float a0 = 0.f, a1 = 0.f, b0 = 0.f, b1 = 0.f;
#pragma unroll 8
    for (int k4 = 0; k4 < 64; ++k4) {
      float4 h4 = *(const float4*)&hs[k4 * 4];
      float4 wa = *(const float4*)&w0[k4 * 4096];
      float4 wb = *(const float4*)&w1[k4 * 4096];
      a0 += wa.x * h4.x + wa.y * h4.y;
      a1 += wa.z * h4.z + wa.w * h4.w;
      b0 += wb.x * h4.x + wb.y * h4.y;
      b1 += wb.z * h4.z + wb.w * h4.w;
    }
    int gb = (t * B_ + b) * G4 + tid;
    float g0 = G[gb] + (a0 + a1) * nd;
    float g1 = G[gb + 512] + (b0 + b1) * nd;
    if (tid >= 256) {
      fo[tid - 256] = sigm(g0);             // f
      fo[tid] = sigm(g1);                   // o
    }
    __syncthreads();
    if (tid < 256) {
      float si = sigm(g0), sg = tanhf(g1);
      float f = fo[tid], oo = fo[256 + tid];
      c = f * (c * nd) + si * sg;
      float h = oo * tanhf(c);
      h_all[(t * B_ + b) * HID + tid] = h;
      hs[tid] = h;
      hlast = h;
    }
  }
  if (tid < 256) { hT[b * HID + tid] = hlast; cT[b * HID + tid] = c; }
}

// ---------------- heads ----------------
__global__ void k_heads(const float* __restrict__ h1, const float* __restrict__ pw,
                        const float* __restrict__ pb, const float* __restrict__ bw,
                        const float* __restrict__ bb, float* __restrict__ out) {
  int idx = blockIdx.x * 256 + threadIdx.x;       // 53248 = 4096 * 13
  int n = idx / 13, o = idx - n * 13;
  const float* h = h1 + n * HID;
  if (o < 12) {
    float acc = pb[o];
    const float* wr = pw + o * HID;
    for (int k = 0; k < HID; ++k) acc += h[k] * wr[k];
    out[n * 12 + o] = acc;
  } else {
    float acc = bb[0];
    for (int k = 0; k < HID; ++k) acc += h[k] * bw[k];
    out[49152 + n] = acc;
  }
}

__global__ void k_argmax(const float* __restrict__ logits, float* __restrict__ action) {
  int n = blockIdx.x * 256 + threadIdx.x;
  float best = logits[n * 12]; int bi = 0;
  for (int o = 1; o < 12; ++o) {
    float v = logits[n * 12 + o];
    if (v > best) { best = v; bi = o; }             // strict > == first-max-wins
  }
  action[n] = (float)bi;
}

extern "C" void kernel_launch(void* const* d_in, const int* in_sizes, int n_in,
                              void* d_out, int out_size, void* d_ws, size_t ws_size,
                              hipStream_t stream) {
  const float* frame = (const float*)d_in[0];
  const unsigned char* done = (const unsigned char*)d_in[1];
  const float* h0 = (const float*)d_in[2];
  const float* c0 = (const float*)d_in[3];
  const float* cw1 = (const float*)d_in[4];  const float* cb1 = (const float*)d_in[5];
  const float* cw2 = (const float*)d_in[6];  const float* cb2 = (const float*)d_in[7];
  const float* cw3 = (const float*)d_in[8];  const float* cb3 = (const float*)d_in[9];
  const float* cw4 = (const float*)d_in[10]; const float* cb4 = (const float*)d_in[11];
  const float* wih0 = (const float*)d_in[12]; const float* whh0 = (const float*)d_in[13];
  const float* bih0 = (const float*)d_in[14]; const float* bhh0 = (const float*)d_in[15];
  const float* wih1 = (const float*)d_in[16]; const float* whh1 = (const float*)d_in[17];
  const float* bih1 = (const float*)d_in[18]; const float* bhh1 = (const float*)d_in[19];
  const float* pw = (const float*)d_in[20]; const float* pb = (const float*)d_in[21];
  const float* bw = (const float*)d_in[22]; const float* bb = (const float*)d_in[23];

  // workspace layout (~132 MB, all f32)
  float* act2  = (float*)d_ws;                      // 15,859,712 (quad-major [n][8][121]x4)
  float* act3  = act2 + 15859712;                   //  4,718,592
  float* feat  = act3 + 4718592;                    //  1,179,648
  float* G0    = feat + 1179648;                    //  4,194,304
  float* G1    = G0 + 4194304;                      //  4,194,304
  float* h0a   = G1 + 4194304;                      //  1,048,576
  float* h1a   = h0a + 1048576;                     //  1,048,576
  float* wih0T = h1a + 1048576;                     //    294,912
  float* wih1T = wih0T + 294912;                    //    262,144
  float* wq0   = wih1T + 262144;                    //    262,144
  float* wq1   = wq0 + 262144;                      //    262,144
  float* wc2   = wq1 + 262144;                      //      9,216
  float* wc3   = wc2 + 9216;
  float* wc4   = wc3 + 9216;
  float* ndb   = wc4 + 9216;                        //      4,096

  float* out = (float*)d_out;
  float* o_hT = out + 57344;
  float* o_cT = out + 90112;

  k_prep<<<4332, 256, 0, stream>>>(wih0, wih1, whh0, whh1, cw2, cw3, cw4,
                                   wih0T, wih1T, wq0, wq1, wc2, wc3, wc4);
  k_donecvt<<<1, 1024, 0, stream>>>(done, ndb);
  k_conv12<<<4096, 512, 0, stream>>>(frame, cw1, cb1, wc2, cb2, act2);
  k_conv3<<<32768, 256, 0, stream>>>(act2, wc3, cb3, act3);
  k_conv4<<<4688, 256, 0, stream>>>(act3, wc4, cb4, feat);
  k_gemm<<<1024, 256, 0, stream>>>(feat, wih0T, bih0, bhh0, G0, 288);
  k_scan<<<64, 512, 0, stream>>>(wq0, G0, h0, c0, ndb, h0a, o_hT, o_cT);
  k_gemm<<<1024, 256, 0, stream>>>(h0a, wih1T, bih1, bhh1, G1, 256);
  k_scan<<<64, 512, 0, stream>>>(wq1, G1, h0 + 16384, c0 + 16384, ndb, h1a,
                                 o_hT + 16384, o_cT + 16384);
  k_heads<<<208, 256, 0, stream>>>(h1a, pw, pb, bw, bb, out);
  k_argmax<<<16, 256, 0, stream>>>(out, out + 53248);
}

// Round 6
// 2007.253 us; speedup vs baseline: 1.5457x; 1.3736x over previous
//
#include <hip/hip_runtime.h>
#include <hip/hip_bf16.h>

// MarioDoomPolicyNet: conv stack (4x stride-2 + ELU) -> 2-layer LSTM scan -> heads.
// R5: conv12 667us (scalar weights + swizzle). ~2ms hidden in sub-top-5 kernels;
//     audit flags k_gemm's 16 s_loads/k-iter as SMEM-bound.
// R6: (1) FULL conv fusion conv1..conv4 in one kernel/image; act1/2/3 in LDS with
//     XOR swizzle (no pad), 79.9KB -> 2 blocks/CU; frame read direct (L1 reuse).
//     (2) GEMM rewritten on transposed activations (featT/h0aT): lane=n coalesced
//     vector load + wave-uniform 64B s_load weights + 16 FMA per k.
//     (3) heads+argmax merged, reading h1aT coalesced with prepacked pwT.
// All f32 (precision requirement established R1/R2: argmax needs exact-ish logits).

#define T_ 64
#define B_ 64
#define NTB 4096
#define HID 256
#define G4 1024

// XOR swizzle for LDS float4 slot j -> float column index (injective, 16B aligned)
#define XS(j) ((((j) << 2)) ^ ((((j) >> 3) & 7) << 2))

__device__ inline float sigm(float x) { return 1.f / (1.f + expf(-x)); }
__device__ inline float elu_(float x) { return x > 0.f ? x : expf(x) - 1.f; }

// ---------------- prep: weight relayouts (all f32) ----------------
__global__ void k_prep(const float* __restrict__ wih0, const float* __restrict__ wih1,
                       const float* __restrict__ whh0, const float* __restrict__ whh1,
                       const float* __restrict__ cw2, const float* __restrict__ cw3,
                       const float* __restrict__ cw4, const float* __restrict__ pw,
                       const float* __restrict__ bw,
                       float* __restrict__ wih0T, float* __restrict__ wih1T,
                       float* __restrict__ wq0, float* __restrict__ wq1,
                       float* __restrict__ wc2, float* __restrict__ wc3,
                       float* __restrict__ wc4, float* __restrict__ pwT) {
  int idx = blockIdx.x * 256 + threadIdx.x;
  if (idx < 294912) {                       // wih0T[k*1024+j] = wih0[j*288+k]
    int k = idx >> 10, j = idx & 1023;
    wih0T[idx] = wih0[j * 288 + k];
  } else if (idx < 557056) {                // wih1T[k*1024+j] = wih1[j*256+k]
    int r = idx - 294912; int k = r >> 10, j = r & 1023;
    wih1T[r] = wih1[j * 256 + k];
  } else if (idx < 819200) {                // wq0[(k4*1024+row)*4+j] = whh0[row][4k4+j]
    int r = idx - 557056;
    int j = r & 3, row = (r >> 2) & 1023, k4 = r >> 12;
    wq0[r] = whh0[row * 256 + k4 * 4 + j];
  } else if (idx < 1081344) {
    int r = idx - 819200;
    int j = r & 3, row = (r >> 2) & 1023, k4 = r >> 12;
    wq1[r] = whh1[row * 256 + k4 * 4 + j];
  } else if (idx < 1108992) {               // conv weights -> [o][tap][i] f32
    int r = idx - 1081344;                  // 3 * 9216
    int which = r / 9216; int d = r - which * 9216;
    int i = d & 31, tap = (d >> 5) % 9, o = d / 288;
    int kh = tap / 3, kw = tap - kh * 3;
    const float* src = which == 0 ? cw2 : (which == 1 ? cw3 : cw4);
    float* dst = which == 0 ? wc2 : (which == 1 ? wc3 : wc4);
    dst[d] = src[((o * 32 + i) * 3 + kh) * 3 + kw];
  } else if (idx < 1113088) {               // pwT[k*16+o]: policy rows 0..11, baseline row 12
    int r = idx - 1108992; int k = r >> 4, o = r & 15;
    pwT[r] = o < 12 ? pw[o * 256 + k] : (o == 12 ? bw[k] : 0.f);
  }
}

// ---------------- done -> notdone float, robust to encoding (verified) ----------------
__global__ __launch_bounds__(1024)
void k_donecvt(const unsigned char* __restrict__ db, float* __restrict__ nd) {
  int tid = threadIdx.x;
  const unsigned* dw = (const unsigned*)db;
  unsigned w = dw[tid];
  int odd = ((w & 0xFFFFFF00u) != 0u && w != 0x3F800000u) ? 1 : 0;
  int any = __syncthreads_count(odd);
  bool u8 = (any > 0);
  for (int j = tid; j < 4096; j += 1024) {
    unsigned v = u8 ? (unsigned)db[j] : dw[j];
    nd[j] = v ? 0.f : 1.f;
  }
}

// ---------------- FUSED conv1..conv4: frame[n] -> featT[k][n] ----------------
// NCHW view: x[n][c][A][B] = frame[n][B][A][c].  All intermediates in LDS.
// LDS: a1t 8x1792 (57344B) + act2l 8x512 (16384B) + act3l 8x192 (6144B) = 79872B -> 2 blk/CU
__global__ __launch_bounds__(512)
void k_convall(const float* __restrict__ frame, const float* __restrict__ cw1,
               const float* __restrict__ cb1, const float* __restrict__ wc2,
               const float* __restrict__ cb2, const float* __restrict__ wc3,
               const float* __restrict__ cb3, const float* __restrict__ wc4,
               const float* __restrict__ cb4, float* __restrict__ featT) {
  __shared__ __align__(16) float a1t[8][1792];   // conv1 out: [oq][swizzled 441 pos x4]
  __shared__ __align__(16) float act2l[8][512];  // conv2 out: [oq][swizzled 121 pos x4]
  __shared__ __align__(16) float act3l[8][192];  // conv3 out: [oq][swizzled 36 pos x4]
  int n = blockIdx.x;
  int tid = threadIdx.x;
  const float4* fp = (const float4*)(frame + (size_t)n * 7056);

  // ---- stage B: conv1 (frame direct from global, L1-cached 9x reuse) ----
  if (tid < 441) {
    int p = tid / 21, q = tid - (tid / 21) * 21;
    float px[9][4];
#pragma unroll
    for (int kh = 0; kh < 3; ++kh) {
#pragma unroll
      for (int kw = 0; kw < 3; ++kw) {
        int A = 2 * p - 1 + kh, Bc = 2 * q - 1 + kw;
        bool ok = ((unsigned)A < 42u) && ((unsigned)Bc < 42u);
        float4 v = ok ? fp[Bc * 42 + A] : make_float4(0.f, 0.f, 0.f, 0.f);
        px[kh * 3 + kw][0] = v.x; px[kh * 3 + kw][1] = v.y;
        px[kh * 3 + kw][2] = v.z; px[kh * 3 + kw][3] = v.w;
      }
    }
    int col = XS(tid);
#pragma unroll
    for (int oq = 0; oq < 8; ++oq) {
      float4 acc;
      float* ap = (float*)&acc;
#pragma unroll
      for (int j = 0; j < 4; ++j) {
        int o = oq * 4 + j;
        float a = cb1[o];
        const float* w = cw1 + o * 36;           // [c][kh][kw], scalar s_load
#pragma unroll
        for (int tap = 0; tap < 9; ++tap)
          a += px[tap][0] * w[tap] + px[tap][1] * w[9 + tap] +
               px[tap][2] * w[18 + tap] + px[tap][3] * w[27 + tap];
        ap[j] = elu_(a);
      }
      *(float4*)&a1t[oq][col] = acc;
    }
  }
  __syncthreads();

  // ---- stage C: conv2 (21x21x32 -> 11x11x32), thread = (pos, o-octet) ----
  {
    int s = tid & 127, oh = tid >> 7;            // oh 0..3, wave-uniform
    int ob = __builtin_amdgcn_readfirstlane(oh << 3);
    if (s < 121) {
      int p = s / 11, q = s - (s / 11) * 11;
      float acc[8];
#pragma unroll
      for (int oi = 0; oi < 8; ++oi) acc[oi] = cb2[ob + oi];
#pragma unroll
      for (int kh = 0; kh < 3; ++kh) {
        int A = 2 * p - 1 + kh;
        if ((unsigned)A >= 21u) continue;
#pragma unroll
        for (int kw = 0; kw < 3; ++kw) {
          int Bc = 2 * q - 1 + kw;
          if ((unsigned)Bc >= 21u) continue;
          int pos = A * 21 + Bc;
          int col = XS(pos);
          int tap = kh * 3 + kw;
#pragma unroll
          for (int i4 = 0; i4 < 8; ++i4) {
            float4 v = *(const float4*)&a1t[i4][col];
#pragma unroll
            for (int oi = 0; oi < 8; ++oi) {
              const float* w = wc2 + ((ob + oi) * 9 + tap) * 32 + i4 * 4;  // s_load
              acc[oi] += v.x * w[0] + v.y * w[1] + v.z * w[2] + v.w * w[3];
            }
          }
        }
      }
      int colw = XS(s);
#pragma unroll
      for (int half = 0; half < 2; ++half) {
        float4 o4 = make_float4(elu_(acc[half * 4 + 0]), elu_(acc[half * 4 + 1]),
                                elu_(acc[half * 4 + 2]), elu_(acc[half * 4 + 3]));
        *(float4*)&act2l[(ob >> 2) + half][colw] = o4;
      }
    }
  }
  __syncthreads();

  // ---- stage D: conv3 (11x11x32 -> 6x6x32), wave = o-quad, lanes = 36 pos ----
  {
    int wv = tid >> 6, lane = tid & 63;
    int oq = __builtin_amdgcn_readfirstlane(wv);
    if (lane < 36) {
      int p = lane / 6, q = lane - (lane / 6) * 6;
      float acc[4];
#pragma unroll
      for (int j = 0; j < 4; ++j) acc[j] = cb3[oq * 4 + j];
#pragma unroll
      for (int kh = 0; kh < 3; ++kh) {
        int A = 2 * p - 1 + kh;
        if ((unsigned)A >= 11u) continue;
#pragma unroll
        for (int kw = 0; kw < 3; ++kw) {
          int Bc = 2 * q - 1 + kw;
          if ((unsigned)Bc >= 11u) continue;
          int col = XS(A * 11 + Bc);
          int tap = kh * 3 + kw;
#pragma unroll
          for (int i4 = 0; i4 < 8; ++i4) {
            float4 v = *(const float4*)&act2l[i4][col];
#pragma unroll
            for (int j = 0; j < 4; ++j) {
              const float* w = wc3 + ((oq * 4 + j) * 9 + tap) * 32 + i4 * 4;  // s_load
              acc[j] += v.x * w[0] + v.y * w[1] + v.z * w[2] + v.w * w[3];
            }
          }
        }
      }
      float4 o4 = make_float4(elu_(acc[0]), elu_(acc[1]), elu_(acc[2]), elu_(acc[3]));
      *(float4*)&act3l[oq][XS(p * 6 + q)] = o4;
    }
  }
  __syncthreads();

  // ---- stage E: conv4 (6x6x32 -> 3x3x32), wave = o-quad, lanes = 9 pos; featT out ----
  {
    int wv = tid >> 6, lane = tid & 63;
    int oq = __builtin_amdgcn_readfirstlane(wv);
    if (lane < 9) {
      int p = lane / 3, q = lane - (lane / 3) * 3;
      float acc[4];
#pragma unroll
      for (int j = 0; j < 4; ++j) acc[j] = cb4[oq * 4 + j];
#pragma unroll
      for (int kh = 0; kh < 3; ++kh) {
        int A = 2 * p - 1 + kh;
        if ((unsigned)A >= 6u) continue;
#pragma unroll
        for (int kw = 0; kw < 3; ++kw) {
          int Bc = 2 * q - 1 + kw;
          if ((unsigned)Bc >= 6u) continue;
          int col = XS(A * 6 + Bc);
          int tap = kh * 3 + kw;
#pragma unroll
          for (int i4 = 0; i4 < 8; ++i4) {
            float4 v = *(const float4*)&act3l[i4][col];
#pragma unroll
            for (int j = 0; j < 4; ++j) {
              const float* w = wc4 + ((oq * 4 + j) * 9 + tap) * 32 + i4 * 4;  // s_load
              acc[j] += v.x * w[0] + v.y * w[1] + v.z * w[2] + v.w * w[3];
            }
          }
        }
      }
#pragma unroll
      for (int j = 0; j < 4; ++j)                // feat k = c*9 + p*3 + q
        featT[(size_t)((oq * 4 + j) * 9 + lane) * 4096 + n] = elu_(acc[j]);
    }
  }
}

// ---------------- GEMM on transposed input: out[n][j] = sum_k inT[k][n]*wT[k][j] + b ----
// lane = n (coalesced vector load), wave-uniform 16-float weight chunk (s_load), 16 FMA/k.
__global__ __launch_bounds__(256)
void k_gemm2(const float* __restrict__ inT, const float* __restrict__ wT,
             const float* __restrict__ b1, const float* __restrict__ b2,
             float* __restrict__ out, int K) {
  int nb = blockIdx.x >> 4, jb = blockIdx.x & 15;
  int lane = threadIdx.x & 63, wv = threadIdx.x >> 6;
  int n = nb * 64 + lane;
  int j0 = jb * 64 + __builtin_amdgcn_readfirstlane(wv << 4);
  float acc[16];
#pragma unroll
  for (int m = 0; m < 16; ++m) acc[m] = 0.f;
  const float* ip = inT + n;
#pragma unroll 4
  for (int k = 0; k < K; ++k) {
    float x = ip[(size_t)k * 4096];
    const float* w = wT + k * 1024 + j0;         // wave-uniform -> s_load x16
#pragma unroll
    for (int m = 0; m < 16; ++m) acc[m] += x * w[m];
  }
  float* op = out + (size_t)n * 1024 + j0;
#pragma unroll
  for (int h = 0; h < 4; ++h) {
    float4 o4 = make_float4(acc[h * 4 + 0] + b1[j0 + h * 4 + 0] + b2[j0 + h * 4 + 0],
                            acc[h * 4 + 1] + b1[j0 + h * 4 + 1] + b2[j0 + h * 4 + 1],
                            acc[h * 4 + 2] + b1[j0 + h * 4 + 2] + b2[j0 + h * 4 + 2],
                            acc[h * 4 + 3] + b1[j0 + h * 4 + 3] + b2[j0 + h * 4 + 3]);
    *(float4*)&op[h * 4] = o4;
  }
}

// ---------------- LSTM scan (one layer): 64 WGs, 1 batch elem each ----------------
// Writes h in transposed layout h_allT[k][t*64+b] for the next GEMM / heads.
__global__ __launch_bounds__(512)
void k_scan(const float* __restrict__ wq, const float* __restrict__ G,
            const float* __restrict__ h_init, const float* __restrict__ c_init,
            const float* __restrict__ ndb, float* __restrict__ h_allT,
            float* __restrict__ hT, float* __restrict__ cT) {
  int b = blockIdx.x, tid = threadIdx.x;
  __shared__ __align__(16) float hs[256];
  __shared__ float fo[512];
  float c = 0.f;
  if (tid < 256) { hs[tid] = h_init[b * HID + tid]; c = c_init[b * HID + tid]; }
  const float* w0 = wq + tid * 4;
  const float* w1 = wq + (tid + 512) * 4;
  float hlast = 0.f;
  for (int t = 0; t < T_; ++t) {
    __syncthreads();                        // hs ready
    float nd = ndb[t * B_ + b];
    float a0 = 0.f, a1 = 0.f, b0 = 0.f, b1 = 0.f;
#pragma unroll 8
    for (int k4 = 0; k4 < 64; ++k4) {
      float4 h4 = *(const float4*)&hs[k4 * 4];
      float4 wa = *(const float4*)&w0[k4 * 4096];
      float4 wb = *(const float4*)&w1[k4 * 4096];
      a0 += wa.x * h4.x + wa.y * h4.y;
      a1 += wa.z * h4.z + wa.w * h4.w;
      b0 += wb.x * h4.x + wb.y * h4.y;
      b1 += wb.z * h4.z + wb.w * h4.w;
    }
    int gb = (t * B_ + b) * G4 + tid;
    float g0 = G[gb] + (a0 + a1) * nd;
    float g1 = G[gb + 512] + (b0 + b1) * nd;
    if (tid >= 256) {
      fo[tid - 256] = sigm(g0);             // f
      fo[tid] = sigm(g1);                   // o
    }
    __syncthreads();
    if (tid < 256) {
      float si = sigm(g0), sg = tanhf(g1);
      float f = fo[tid], oo = fo[256 + tid];
      c = f * (c * nd) + si * sg;
      float h = oo * tanhf(c);
      h_allT[(size_t)tid * 4096 + t * 64 + b] = h;
      hs[tid] = h;
      hlast = h;
    }
  }
  if (tid < 256) { hT[b * HID + tid] = hlast; cT[b * HID + tid] = c; }
}

// ---------------- heads + argmax (merged): thread = n, reads h1aT coalesced ----------
__global__ __launch_bounds__(256)
void k_heads(const float* __restrict__ h1aT, const float* __restrict__ pwT,
             const float* __restrict__ pb, const float* __restrict__ bb,
             float* __restrict__ out) {
  int n = blockIdx.x * 256 + threadIdx.x;
  float acc[13];
#pragma unroll
  for (int o = 0; o < 12; ++o) acc[o] = pb[o];
  acc[12] = bb[0];
  for (int k = 0; k < 256; ++k) {
    float h = h1aT[(size_t)k * 4096 + n];
    const float* w = pwT + k * 16;               // uniform -> s_load
#pragma unroll
    for (int o = 0; o < 13; ++o) acc[o] += h * w[o];
  }
  float best = acc[0]; int bi = 0;
#pragma unroll
  for (int o = 1; o < 12; ++o)
    if (acc[o] > best) { best = acc[o]; bi = o; }   // strict > == first-max-wins
#pragma unroll
  for (int o = 0; o < 12; ++o) out[n * 12 + o] = acc[o];
  out[49152 + n] = acc[12];
  out[53248 + n] = (float)bi;
}

extern "C" void kernel_launch(void* const* d_in, const int* in_sizes, int n_in,
                              void* d_out, int out_size, void* d_ws, size_t ws_size,
                              hipStream_t stream) {
  const float* frame = (const float*)d_in[0];
  const unsigned char* done = (const unsigned char*)d_in[1];
  const float* h0 = (const float*)d_in[2];
  const float* c0 = (const float*)d_in[3];
  const float* cw1 = (const float*)d_in[4];  const float* cb1 = (const float*)d_in[5];
  const float* cw2 = (const float*)d_in[6];  const float* cb2 = (const float*)d_in[7];
  const float* cw3 = (const float*)d_in[8];  const float* cb3 = (const float*)d_in[9];
  const float* cw4 = (const float*)d_in[10]; const float* cb4 = (const float*)d_in[11];
  const float* wih0 = (const float*)d_in[12]; const float* whh0 = (const float*)d_in[13];
  const float* bih0 = (const float*)d_in[14]; const float* bhh0 = (const float*)d_in[15];
  const float* wih1 = (const float*)d_in[16]; const float* whh1 = (const float*)d_in[17];
  const float* bih1 = (const float*)d_in[18]; const float* bhh1 = (const float*)d_in[19];
  const float* pw = (const float*)d_in[20]; const float* pb = (const float*)d_in[21];
  const float* bw = (const float*)d_in[22]; const float* bb = (const float*)d_in[23];

  // workspace layout (~51 MB, all f32)
  float* featT = (float*)d_ws;                      //  1,179,648  [288][4096]
  float* G0    = featT + 1179648;                   //  4,194,304
  float* G1    = G0 + 4194304;                      //  4,194,304
  float* h0aT  = G1 + 4194304;                      //  1,048,576  [256][4096]
  float* h1aT  = h0aT + 1048576;                    //  1,048,576
  float* wih0T = h1aT + 1048576;                    //    294,912
  float* wih1T = wih0T + 294912;                    //    262,144
  float* wq0   = wih1T + 262144;                    //    262,144
  float* wq1   = wq0 + 262144;                      //    262,144
  float* wc2   = wq1 + 262144;                      //      9,216
  float* wc3   = wc2 + 9216;
  float* wc4   = wc3 + 9216;
  float* pwT   = wc4 + 9216;                        //      4,096
  float* ndb   = pwT + 4096;                        //      4,096

  float* out = (float*)d_out;
  float* o_hT = out + 57344;
  float* o_cT = out + 90112;

  k_prep<<<4348, 256, 0, stream>>>(wih0, wih1, whh0, whh1, cw2, cw3, cw4, pw, bw,
                                   wih0T, wih1T, wq0, wq1, wc2, wc3, wc4, pwT);
  k_donecvt<<<1, 1024, 0, stream>>>(done, ndb);
  k_convall<<<4096, 512, 0, stream>>>(frame, cw1, cb1, wc2, cb2, wc3, cb3, wc4, cb4,
                                      featT);
  k_gemm2<<<1024, 256, 0, stream>>>(featT, wih0T, bih0, bhh0, G0, 288);
  k_scan<<<64, 512, 0, stream>>>(wq0, G0, h0, c0, ndb, h0aT, o_hT, o_cT);
  k_gemm2<<<1024, 256, 0, stream>>>(h0aT, wih1T, bih1, bhh1, G1, 256);
  k_scan<<<64, 512, 0, stream>>>(wq1, G1, h0 + 16384, c0 + 16384, ndb, h1aT,
                                 o_hT + 16384, o_cT + 16384);
  k_heads<<<16, 256, 0, stream>>>(h1aT, pwT, pb, bb, out);
}